// Round 6
// baseline (87.234 us; speedup 1.0000x reference)
//
#include <hip/hip_runtime.h>

// PatchChamferDistance: B=32, G=64, P=256, D=3 -> BG=2048 patches.
// dist2[i][j] = ||p_i||^2 + ||t_j||^2 - 2 p_i.t_j (clamped >= 0)
// out = mean over patches of (mean_i min_j + mean_j min_i)
//
// Round 6: rounds 1/3/5 all timed 84.0+-0.2 us with kernels differing ~15% in
// VALU and ~25% in DS ops -> kernel ~13 us VALU-bound, dur dominated by the
// harness 42 us ws-poison fill + restores + launches. Attack the launch side:
//  - fuse the final reduction: one RELAXED device-scope float atomicAdd of the
//    scaled block sum into d_out (round 4's disaster was the per-block
//    __threadfence + acq_rel counter, NOT the plain atomic). d_out zeroed by
//    our own 4-byte memset node (graph-capturable, proven in round 4).
//  - 2 patches per block, grid=1024 = exactly one 4-block/CU dispatch batch:
//    halves block-launch overhead and atomic count.
// Inner loop: round-5 proven form (fma chain + v_min3, norm plane in LDS).

#define NPATCH 2048
#define NPTS   256

typedef float v4f __attribute__((ext_vector_type(4)));

__global__ __launch_bounds__(256, 4) void chamfer_kernel(
    const float* __restrict__ pred,
    const float* __restrict__ tgt,
    float* __restrict__ out)
{
    __shared__ float sP[4][NPTS];    // pred planes x,y,z,norm
    __shared__ float sT[4][NPTS];    // tgt  planes x,y,z,norm
    __shared__ float mhalf[2][NPTS]; // per-dir partial mins from half==1 waves
    __shared__ float red[2];

    const int tid  = threadIdx.x;
    const int wave = tid >> 6;     // 0,1: forward  2,3: backward
    const int lane = tid & 63;
    const int dir  = wave >> 1;    // 0: queries=pred stream=tgt; 1: swapped
    const int half = wave & 1;     // which 128-long j half this wave streams

    float blocksum = 0.0f;

#pragma unroll 1
    for (int pp = 0; pp < 2; ++pp) {
        const int patch = blockIdx.x * 2 + pp;

        __syncthreads();   // protect LDS reuse across the patch loop

        // Stage both point sets into SoA LDS planes + norm plane.
        {
            const float* __restrict__ pb = pred + (size_t)patch * (NPTS * 3);
            const float* __restrict__ tb = tgt  + (size_t)patch * (NPTS * 3);
            float x = pb[3 * tid + 0], y = pb[3 * tid + 1], z = pb[3 * tid + 2];
            sP[0][tid] = x; sP[1][tid] = y; sP[2][tid] = z;
            sP[3][tid] = fmaf(z, z, fmaf(y, y, x * x));
            x = tb[3 * tid + 0]; y = tb[3 * tid + 1]; z = tb[3 * tid + 2];
            sT[0][tid] = x; sT[1][tid] = y; sT[2][tid] = z;
            sT[3][tid] = fmaf(z, z, fmaf(y, y, x * x));
        }
        __syncthreads();

        const float (*Q)[NPTS] = (dir == 0) ? sP : sT;
        const float (*S)[NPTS] = (dir == 0) ? sT : sP;

        // 4 query points per lane: (-2x,-2y,-2z), norm on the side.
        float qx[4], qy[4], qz[4], qn[4], m[4];
#pragma unroll
        for (int q = 0; q < 4; ++q) {
            const int p = lane + 64 * q;
            qx[q] = -2.0f * Q[0][p];
            qy[q] = -2.0f * Q[1][p];
            qz[q] = -2.0f * Q[2][p];
            qn[q] = Q[3][p];
            m[q]  = 1e30f;
        }

        const int jbase = half * (NPTS / 2);
        const float* __restrict__ Sx = &S[0][jbase];
        const float* __restrict__ Sy = &S[1][jbase];
        const float* __restrict__ Sz = &S[2][jbase];
        const float* __restrict__ Sn = &S[3][jbase];

#pragma unroll 4
        for (int jj = 0; jj < NPTS / 2; jj += 4) {
            const v4f x4 = *(const v4f*)(Sx + jj);
            const v4f y4 = *(const v4f*)(Sy + jj);
            const v4f z4 = *(const v4f*)(Sz + jj);
            const v4f n4 = *(const v4f*)(Sn + jj);
#pragma unroll
            for (int q = 0; q < 4; ++q) {
                const float da = fmaf(qx[q], x4.x, fmaf(qy[q], y4.x, fmaf(qz[q], z4.x, n4.x)));
                const float db = fmaf(qx[q], x4.y, fmaf(qy[q], y4.y, fmaf(qz[q], z4.y, n4.y)));
                m[q] = fminf(m[q], fminf(da, db));   // v_min3_f32
                const float dc = fmaf(qx[q], x4.z, fmaf(qy[q], y4.z, fmaf(qz[q], z4.z, n4.z)));
                const float dd = fmaf(qx[q], x4.w, fmaf(qy[q], y4.w, fmaf(qz[q], z4.w, n4.w)));
                m[q] = fminf(m[q], fminf(dc, dd));   // v_min3_f32
            }
        }

        // Upper-half waves publish per-query mins; lower-half waves combine.
        if (half == 1) {
#pragma unroll
            for (int q = 0; q < 4; ++q)
                mhalf[dir][lane + 64 * q] = m[q];
        }
        __syncthreads();

        if (half == 0) {
            float s = 0.0f;
#pragma unroll
            for (int q = 0; q < 4; ++q) {
                const float mm = fminf(m[q], mhalf[dir][lane + 64 * q]);
                s += fmaxf(qn[q] + mm, 0.0f);
            }
#pragma unroll
            for (int off = 32; off > 0; off >>= 1)
                s += __shfl_down(s, off, 64);
            if (lane == 0) red[dir] = s;
        }
        __syncthreads();
        if (tid == 0) blocksum += red[0] + red[1];
    }

    // One relaxed, fire-and-forget device-scope atomic per block. No fence,
    // no counter, no read-back (round-4 lesson).
    if (tid == 0)
        atomicAdd(out, blocksum * (1.0f / ((float)NPTS * (float)NPATCH)));
}

extern "C" void kernel_launch(void* const* d_in, const int* in_sizes, int n_in,
                              void* d_out, int out_size, void* d_ws, size_t ws_size,
                              hipStream_t stream) {
    const float* pred = (const float*)d_in[0];
    const float* tgt  = (const float*)d_in[1];
    float* out        = (float*)d_out;

    hipMemsetAsync(out, 0, sizeof(float), stream);  // d_out is poisoned 0xAA
    chamfer_kernel<<<NPATCH / 2, 256, 0, stream>>>(pred, tgt, out);
}

// Round 7
// 81.090 us; speedup vs baseline: 1.0758x; 1.0758x over previous
//
#include <hip/hip_runtime.h>

// PatchChamferDistance: B=32, G=64, P=256, D=3 -> BG=2048 patches.
// dist2[i][j] = ||p_i||^2 + ||t_j||^2 - 2 p_i.t_j (clamped >= 0)
// out = mean over patches of (mean_i min_j + mean_j min_i)
//
// Round 7: MFMA rewrite. Established: r1/r3/r5 all 84.0+-0.2 us with a ~13 us
// VALU-bound kernel (each pair computed twice, 3.5 slots/dist); both fusion
// attempts (r4 fence storm, r6 atomic+small grid) regressed -> keep the
// two-kernel skeleton, replace the inner loop with mfma_f32_16x16x32_f16:
//  - one MFMA = full 16x16 dist2 tile, BOTH directions reduced from it
//    (6 VALU/tile: 4 v_min rowmin + 2 v_min3 colmin)
//  - A = {-2x,-2y,-2z,1,1,0,0,0}, B = {x,y,z,tn_hi,tn_lo,0,0,0} (tn split
//    into two f16s -> tn exact to ~1e-5), C-init = pn (fp32, exact):
//    D = pn + tn - 2 p.t with zero per-tile add cost.
//  - robustness: A/B share the (quad,slot)->k map, so any consistent HW k
//    permutation gives the same dot product; C/D layout col=lane&15,
//    row=quad*4+reg (m89-verified, dtype-independent).
// Precision: only coords quantized (f16 RTNE, symmetric): dist2 err ~2e-3,
// threshold 7.93e-3.

#define NPATCH 2048
#define NPTS   256

typedef _Float16 f16x8 __attribute__((ext_vector_type(8)));
typedef float    f32x4 __attribute__((ext_vector_type(4)));

__global__ __launch_bounds__(256, 2) void chamfer_mfma_kernel(
    const float* __restrict__ pred,
    const float* __restrict__ tgt,
    float* __restrict__ partial)
{
    __shared__ __align__(16) float sP[4][4][NPTS];  // 4 patches x {x,y,z,norm}
    __shared__ __align__(16) float sT[4][4][NPTS];

    const int tid = threadIdx.x;

    // Stage 4 patches' SoA planes (whole block cooperates).
    {
        const size_t pbase = (size_t)blockIdx.x * 4 * (NPTS * 3);
#pragma unroll
        for (int pp = 0; pp < 4; ++pp) {
            const float* __restrict__ pb = pred + pbase + pp * (NPTS * 3);
            const float* __restrict__ tb = tgt  + pbase + pp * (NPTS * 3);
            float x = pb[3 * tid + 0], y = pb[3 * tid + 1], z = pb[3 * tid + 2];
            sP[pp][0][tid] = x; sP[pp][1][tid] = y; sP[pp][2][tid] = z;
            sP[pp][3][tid] = fmaf(z, z, fmaf(y, y, x * x));
            x = tb[3 * tid + 0]; y = tb[3 * tid + 1]; z = tb[3 * tid + 2];
            sT[pp][0][tid] = x; sT[pp][1][tid] = y; sT[pp][2][tid] = z;
            sT[pp][3][tid] = fmaf(z, z, fmaf(y, y, x * x));
        }
    }
    __syncthreads();

    const int wave = tid >> 6;      // one wave = one patch
    const int lane = tid & 63;
    const int c    = lane & 15;     // col within tile
    const int quad = lane >> 4;
    const bool q0  = (quad == 0);
    const int pp   = wave;

    const f16x8 zf = {};            // zero frag (quads 1-3 carry k>=8: all zero)

    // Build the 16 B-frags (target points) once; colmin accumulators.
    f16x8 bfrag[16];
    float colmin[16];
#pragma unroll
    for (int jb = 0; jb < 16; ++jb) {
        const int idx = jb * 16 + c;
        const float x = sT[pp][0][idx], y = sT[pp][1][idx], z = sT[pp][2][idx];
        const float tn = sT[pp][3][idx];
        const _Float16 th = (_Float16)tn;                 // RTNE
        const _Float16 tl = (_Float16)(tn - (float)th);   // residual
        f16x8 bv = {(_Float16)x, (_Float16)y, (_Float16)z, th, tl,
                    (_Float16)0, (_Float16)0, (_Float16)0};
        bfrag[jb] = q0 ? bv : zf;
        colmin[jb] = 1e30f;
    }

    float sf = 0.0f, sb = 0.0f;

#pragma unroll 1
    for (int ib = 0; ib < 16; ++ib) {
        // A-frag for this row-block: {-2x,-2y,-2z,1,1,0,0,0} on quad0.
        const int idx = ib * 16 + c;
        const float x = sP[pp][0][idx], y = sP[pp][1][idx], z = sP[pp][2][idx];
        f16x8 av = {(_Float16)(-2.0f * x), (_Float16)(-2.0f * y),
                    (_Float16)(-2.0f * z), (_Float16)1.0f, (_Float16)1.0f,
                    (_Float16)0, (_Float16)0, (_Float16)0};
        const f16x8 afrag = q0 ? av : zf;
        // C-init = pn for this lane's 4 rows (fp32 exact).
        const f32x4 pnv = *(const f32x4*)&sP[pp][3][ib * 16 + quad * 4];

        float r0 = 1e30f, r1 = 1e30f, r2 = 1e30f, r3 = 1e30f;
#pragma unroll
        for (int jb = 0; jb < 16; ++jb) {
            const f32x4 d = __builtin_amdgcn_mfma_f32_16x16x32_f16(
                afrag, bfrag[jb], pnv, 0, 0, 0);
            r0 = fminf(r0, d.x); r1 = fminf(r1, d.y);
            r2 = fminf(r2, d.z); r3 = fminf(r3, d.w);
            const float t = fminf(fminf(d.x, d.y), d.z);          // v_min3
            colmin[jb] = fminf(fminf(t, d.w), colmin[jb]);        // v_min3
        }
        // rowmin: min over the 16 cols held by this quad's lanes.
#pragma unroll
        for (int dlt = 1; dlt < 16; dlt <<= 1) {
            r0 = fminf(r0, __shfl_xor(r0, dlt, 64));
            r1 = fminf(r1, __shfl_xor(r1, dlt, 64));
            r2 = fminf(r2, __shfl_xor(r2, dlt, 64));
            r3 = fminf(r3, __shfl_xor(r3, dlt, 64));
        }
        // each row now duplicated across 16 lanes -> scale by 1/16 later
        sf += fmaxf(r0, 0.0f) + fmaxf(r1, 0.0f) +
              fmaxf(r2, 0.0f) + fmaxf(r3, 0.0f);
    }

    // colmin: min across the 4 quads; each col duplicated x4 -> scale 1/4.
#pragma unroll
    for (int jb = 0; jb < 16; ++jb) {
        float v = colmin[jb];
        v = fminf(v, __shfl_xor(v, 16, 64));
        v = fminf(v, __shfl_xor(v, 32, 64));
        sb += fmaxf(v, 0.0f);
    }

    float tot = sf * (1.0f / 16.0f) + sb * (1.0f / 4.0f);
#pragma unroll
    for (int off = 32; off > 0; off >>= 1)
        tot += __shfl_down(tot, off, 64);
    if (lane == 0) partial[blockIdx.x * 4 + wave] = tot;
}

__global__ __launch_bounds__(256) void chamfer_reduce_kernel(
    const float* __restrict__ partial,
    float* __restrict__ out)
{
    __shared__ float red[4];
    const int tid = threadIdx.x;
    float s = 0.0f;
#pragma unroll
    for (int i = tid; i < NPATCH; i += 256) s += partial[i];
#pragma unroll
    for (int off = 32; off > 0; off >>= 1)
        s += __shfl_down(s, off, 64);
    if ((tid & 63) == 0) red[tid >> 6] = s;
    __syncthreads();
    if (tid == 0)
        out[0] = (red[0] + red[1] + red[2] + red[3]) *
                 (1.0f / ((float)NPTS * (float)NPATCH));
}

extern "C" void kernel_launch(void* const* d_in, const int* in_sizes, int n_in,
                              void* d_out, int out_size, void* d_ws, size_t ws_size,
                              hipStream_t stream) {
    const float* pred = (const float*)d_in[0];
    const float* tgt  = (const float*)d_in[1];
    float* partial    = (float*)d_ws;      // 2048 floats = 8 KB scratch
    float* out        = (float*)d_out;

    chamfer_mfma_kernel<<<NPATCH / 4, 256, 0, stream>>>(pred, tgt, partial);
    chamfer_reduce_kernel<<<1, 256, 0, stream>>>(partial, out);
}